// Round 7
// baseline (270.524 us; speedup 1.0000x reference)
//
#include <hip/hip_runtime.h>
#include <hip/hip_bf16.h>

#define N_NODES 100000
#define N_EDGES 3200000

#define P_PARTS 7
#define PART    16384                    // 7*16384 = 114688 >= N; p = dst>>14
#define CBLOCKS 1024
#define EPB     (N_EDGES / CBLOCKS)      // 3125 exact
#define CHUNKS  64
#define HBLOCKS (P_PARTS * CHUNKS)       // 448
#define T_HIST  1024

// ---------------- workspace layout (bytes) ----------------
#define OFF_STATS   0         // double[5]          (zeroed)
#define OFF_CONST   64        // float[130]: A32,B32,C32,U32,GB,SCC
#define OFF_DEG     1024      // float[114688]      (zeroed)  [ends 459776]
#define OFF_ACC     459776    // float[114688]
#define OFF_DINV    918528    // float[100000]
#define OFF_GS      1318528   // float[100000]
#define OFF_BCNT    1718528   // int[1024*7]
#define OFF_BBASE   1747200   // int[1024*7]
#define OFF_PBASE   1775872   // int[8]
#define OFF_BUCKET  1775936   // uint[3200000]  [ends ~14.6 MB]

// per-wave int64-vs-int32 detection: high words of first 64 int64 slots
__device__ __forceinline__ bool detect_is64(const void* ei) {
    const int* p = (const int*)ei;
    int lane = threadIdx.x & 63;
    int hi = p[2 * lane + 1];
    unsigned long long m = __ballot(hi != 0);
    return m == 0ull;  // wave-uniform
}

// ---- K1: BN stats + per-block per-partition edge counts (register counters) ----
__global__ __launch_bounds__(256) void count_stats_kernel(
        const float* __restrict__ x, const void* __restrict__ ei,
        double* __restrict__ stats, int* __restrict__ blockcnt) {
    __shared__ int scnt[P_PARTS][4];
    __shared__ double sh[5][4];
    bool is64 = detect_is64(ei);
    int lane = threadIdx.x & 63, w = threadIdx.x >> 6;

    // ---- stats: one node per thread (1024*256 >= N) ----
    {
        double a0 = 0, a1 = 0, a2 = 0, a3 = 0, a4 = 0;
        int n = blockIdx.x * 256 + threadIdx.x;
        if (n < N_NODES) {
            float2 v = ((const float2*)x)[n];
            double x0 = v.x, x1 = v.y;
            a0 = x0; a1 = x1; a2 = x0 * x0; a3 = x1 * x1; a4 = x0 * x1;
        }
        for (int off = 32; off; off >>= 1) {
            a0 += __shfl_down(a0, off);
            a1 += __shfl_down(a1, off);
            a2 += __shfl_down(a2, off);
            a3 += __shfl_down(a3, off);
            a4 += __shfl_down(a4, off);
        }
        if (lane == 0) {
            sh[0][w] = a0; sh[1][w] = a1; sh[2][w] = a2; sh[3][w] = a3; sh[4][w] = a4;
        }
        __syncthreads();
        if (threadIdx.x == 0) {
            double t0 = 0, t1 = 0, t2 = 0, t3 = 0, t4 = 0;
            for (int i = 0; i < 4; i++) {
                t0 += sh[0][i]; t1 += sh[1][i]; t2 += sh[2][i]; t3 += sh[3][i]; t4 += sh[4][i];
            }
            atomicAdd(&stats[0], t0);
            atomicAdd(&stats[1], t1);
            atomicAdd(&stats[2], t2);
            atomicAdd(&stats[3], t3);
            atomicAdd(&stats[4], t4);
        }
    }

    // ---- per-thread register counts, zero LDS traffic in loop ----
    int cnt[P_PARTS];
#pragma unroll
    for (int pp = 0; pp < P_PARTS; pp++) cnt[pp] = 0;
    int e0 = blockIdx.x * EPB, e1 = e0 + EPB;
    if (is64) {
        const long long* dstp = (const long long*)ei + N_EDGES;
        for (int e = e0 + threadIdx.x; e < e1; e += 256) {
            int p = ((int)dstp[e]) >> 14;
#pragma unroll
            for (int pp = 0; pp < P_PARTS; pp++) cnt[pp] += (p == pp);
        }
    } else {
        const int* dstp = (const int*)ei + N_EDGES;
        for (int e = e0 + threadIdx.x; e < e1; e += 256) {
            int p = dstp[e] >> 14;
#pragma unroll
            for (int pp = 0; pp < P_PARTS; pp++) cnt[pp] += (p == pp);
        }
    }
#pragma unroll
    for (int pp = 0; pp < P_PARTS; pp++) {
        int v = cnt[pp];
        for (int off = 32; off; off >>= 1) v += __shfl_down(v, off);
        if (lane == 0) scnt[pp][w] = v;
    }
    __syncthreads();
    if (threadIdx.x < P_PARTS) {
        int t = threadIdx.x;
        blockcnt[blockIdx.x * P_PARTS + t] = scnt[t][0] + scnt[t][1] + scnt[t][2] + scnt[t][3];
    }
}

// ---- K2 (1 block): exact bucket bases via scan + encoder/head constants ----
__global__ __launch_bounds__(1024) void scan_consts_kernel(
        const int* __restrict__ blockcnt, int* __restrict__ blockbase, int* __restrict__ pbase,
        const double* __restrict__ stats,
        const float* __restrict__ w1, const float* __restrict__ b1,
        const float* __restrict__ gamma, const float* __restrict__ beta,
        const float* __restrict__ w2, const float* __restrict__ b2,
        const float* __restrict__ gcn_w, const float* __restrict__ wb,
        const float* __restrict__ gcn_b, const float* __restrict__ bb,
        float* __restrict__ consts) {
    __shared__ int wsum[16];
    __shared__ int tot[P_PARTS];
    __shared__ int pb[P_PARTS + 1];
    __shared__ float sV[32];
    int t = threadIdx.x;
    int lane = t & 63, w = t >> 6;
    int rx[P_PARTS];

    for (int p = 0; p < P_PARTS; p++) {
        int v = blockcnt[t * P_PARTS + p];
        int sv = v;
        for (int off = 1; off < 64; off <<= 1) {
            int u = __shfl_up(sv, off, 64);
            if (lane >= off) sv += u;
        }
        if (lane == 63) wsum[w] = sv;
        __syncthreads();
        if (w == 0) {
            int pv = (lane < 16) ? wsum[lane] : 0;
            for (int off = 1; off < 16; off <<= 1) {
                int u = __shfl_up(pv, off, 64);
                if (lane >= off) pv += u;
            }
            if (lane < 16) wsum[lane] = pv;
        }
        __syncthreads();
        int incl = sv + (w > 0 ? wsum[w - 1] : 0);
        rx[p] = incl - v;
        if (t == 1023) tot[p] = incl;
        __syncthreads();
    }
    if (t == 0) {
        int run = 0;
        for (int p = 0; p < P_PARTS; p++) { pb[p] = run; run += tot[p]; }
        pb[P_PARTS] = run;
        for (int p = 0; p <= P_PARTS; p++) pbase[p] = pb[p];
    }
    __syncthreads();
    for (int p = 0; p < P_PARTS; p++)
        blockbase[t * P_PARTS + p] = rx[p] + pb[p];

    // ---- constants ----
    if (t < 32) {
        int c = t;
        double invN = 1.0 / (double)N_NODES;
        double m0 = stats[0] * invN, m1 = stats[1] * invN;
        double e00 = stats[2] * invN, e11 = stats[3] * invN, e01 = stats[4] * invN;
        double a = w1[2 * c], b = w1[2 * c + 1], tt = b1[c];
        double meanH = a * m0 + b * m1 + tt;
        double eh2 = a * a * e00 + b * b * e11 + 2.0 * a * b * e01 +
                     2.0 * tt * (a * m0 + b * m1) + tt * tt;
        double var = eh2 - meanH * meanH;
        double inv = 1.0 / sqrt(var + 1e-5);
        float sc = (float)((double)gamma[c] * inv);
        float shift = beta[c] - (float)meanH * sc;
        consts[c]      = (float)a * sc;
        consts[32 + c] = (float)b * sc;
        consts[64 + c] = (float)tt * sc + shift;
        float vc = 0.f;
        for (int j = 0; j < 32; j++) vc += wb[j] * gcn_w[j * 32 + c];
        sV[c] = vc;
    }
    __syncthreads();
    if (t < 32) {
        float u = 0.f;
        for (int c = 0; c < 32; c++) u += sV[c] * w2[c * 32 + t];
        consts[96 + t] = u;
        float gb = b2[t] * sV[t];
        for (int off = 16; off; off >>= 1) gb += __shfl_down(gb, off, 32);
        float pv = wb[t] * gcn_b[t];
        for (int off = 16; off; off >>= 1) pv += __shfl_down(pv, off, 32);
        if (t == 0) {
            consts[128] = gb;
            consts[129] = pv + bb[0];
        }
    }
}

// ---- K3: compact edges into partition buckets (wave-ballot ranking) ----
__global__ __launch_bounds__(256) void compact_kernel(
        const void* __restrict__ ei, const int* __restrict__ blockbase,
        unsigned* __restrict__ bucket) {
    __shared__ int rank[P_PARTS];
    __shared__ int bbase[P_PARTS];
    if (threadIdx.x < P_PARTS) {
        rank[threadIdx.x] = 0;
        bbase[threadIdx.x] = blockbase[blockIdx.x * P_PARTS + threadIdx.x];
    }
    bool is64 = detect_is64(ei);
    __syncthreads();
    int lane = threadIdx.x & 63;
    unsigned long long below = (lane == 63) ? ~0ull >> 1 : (1ull << lane) - 1;
    int e0 = blockIdx.x * EPB, e1 = e0 + EPB;
    const long long* srcp64 = (const long long*)ei;
    const long long* dstp64 = srcp64 + N_EDGES;
    const int* srcp32 = (const int*)ei;
    const int* dstp32 = srcp32 + N_EDGES;

    for (int it = 0; it < EPB; it += 256) {
        int e = e0 + it + threadIdx.x;
        bool valid = e < e1;
        int p = -1;
        unsigned packed = 0;
        if (valid) {
            int s, d;
            if (is64) { s = (int)srcp64[e]; d = (int)dstp64[e]; }
            else      { s = srcp32[e];      d = dstp32[e]; }
            p = d >> 14;
            packed = (unsigned)s | ((unsigned)(d & 16383) << 17);
        }
#pragma unroll
        for (int pp = 0; pp < P_PARTS; pp++) {
            unsigned long long m = __ballot(p == pp);
            if (m) {
                int leader = __ffsll((long long)m) - 1;
                int basepos = 0;
                if (lane == leader) basepos = atomicAdd(&rank[pp], __popcll(m));
                basepos = __shfl(basepos, leader, 64);
                if (p == pp)
                    bucket[bbase[pp] + basepos + __popcll(m & below)] = packed;
            }
        }
    }
}

// ---- K4: degree histogram from buckets (single-read) ----
__global__ __launch_bounds__(T_HIST, 2) void deg_hist_kernel(
        const unsigned* __restrict__ bucket, const int* __restrict__ pbase,
        float* __restrict__ degf) {
    __shared__ float hist[PART];
    int p = blockIdx.x % P_PARTS;
    int chunk = blockIdx.x / P_PARTS;
    for (int i = threadIdx.x; i < PART; i += T_HIST) hist[i] = 0.f;
    int b0 = pbase[p], b1 = pbase[p + 1];
    int cnt = b1 - b0;
    int per = (cnt + CHUNKS - 1) / CHUNKS;
    int lo = b0 + chunk * per;
    int hi = min(lo + per, b1);
    __syncthreads();
    int i = lo + threadIdx.x;
    for (; i + T_HIST < hi; i += 2 * T_HIST) {
        unsigned a = bucket[i];
        unsigned b = bucket[i + T_HIST];
        atomicAdd(&hist[a >> 17], 1.0f);
        atomicAdd(&hist[b >> 17], 1.0f);
    }
    if (i < hi) atomicAdd(&hist[bucket[i] >> 17], 1.0f);
    __syncthreads();
    int base = p << 14;
    for (int k = threadIdx.x; k < PART; k += T_HIST) {
        float v = hist[k];
        if (v != 0.f) unsafeAtomicAdd(&degf[base + k], v);
    }
}

// ---- K5: encoder (scalar): gs[n] = dinv * (GB + sum_c PReLU(Ax0+Bx1+C) U[c]) ----
__global__ void encoder_kernel(const float* __restrict__ x, const float* __restrict__ consts,
                               const float* __restrict__ prelu_a, const float* __restrict__ degf,
                               float* __restrict__ dinv, float* __restrict__ gs,
                               float* __restrict__ acc) {
    __shared__ float sA[32], sB[32], sC[32], sU[32];
    __shared__ float sGB;
    if (threadIdx.x < 32) {
        sA[threadIdx.x] = consts[threadIdx.x];
        sB[threadIdx.x] = consts[32 + threadIdx.x];
        sC[threadIdx.x] = consts[64 + threadIdx.x];
        sU[threadIdx.x] = consts[96 + threadIdx.x];
    }
    if (threadIdx.x == 0) sGB = consts[128];
    __syncthreads();
    float alpha = prelu_a[0];
    int n = blockIdx.x * blockDim.x + threadIdx.x;
    if (n < N_NODES) {
        float2 xv = ((const float2*)x)[n];
        float g = sGB;
#pragma unroll
        for (int c = 0; c < 32; c++) {
            float hb = sA[c] * xv.x + sB[c] * xv.y + sC[c];
            float pc = hb >= 0.f ? hb : alpha * hb;
            g += pc * sU[c];
        }
        float di = rsqrtf(degf[n] + 1.0f);
        float gg = di * g;
        dinv[n] = di;
        gs[n] = gg;
        acc[n] = gg;  // self-loop term; finalize multiplies by dinv
    }
}

// ---- K6: scatter from buckets (single-read) ----
__global__ __launch_bounds__(T_HIST, 2) void scatter_hist_kernel(
        const unsigned* __restrict__ bucket, const int* __restrict__ pbase,
        const float* __restrict__ gs, float* __restrict__ acc) {
    __shared__ float hist[PART];
    int p = blockIdx.x % P_PARTS;
    int chunk = blockIdx.x / P_PARTS;
    for (int i = threadIdx.x; i < PART; i += T_HIST) hist[i] = 0.f;
    int b0 = pbase[p], b1 = pbase[p + 1];
    int cnt = b1 - b0;
    int per = (cnt + CHUNKS - 1) / CHUNKS;
    int lo = b0 + chunk * per;
    int hi = min(lo + per, b1);
    __syncthreads();
    int i = lo + threadIdx.x;
    for (; i + T_HIST < hi; i += 2 * T_HIST) {
        unsigned a = bucket[i];
        unsigned b = bucket[i + T_HIST];
        float va = gs[a & 0x1FFFF];
        float vb = gs[b & 0x1FFFF];
        atomicAdd(&hist[a >> 17], va);
        atomicAdd(&hist[b >> 17], vb);
    }
    if (i < hi) {
        unsigned a = bucket[i];
        atomicAdd(&hist[a >> 17], gs[a & 0x1FFFF]);
    }
    __syncthreads();
    int base = p << 14;
    for (int k = threadIdx.x; k < PART; k += T_HIST) {
        float v = hist[k];
        if (v != 0.f) unsafeAtomicAdd(&acc[base + k], v);
    }
}

// ---- K7: finalize ----
__global__ void finalize_kernel(const float* __restrict__ dinv, const float* __restrict__ acc,
                                const float* __restrict__ consts, float* __restrict__ out) {
    int n = blockIdx.x * blockDim.x + threadIdx.x;
    if (n < N_NODES) out[n] = dinv[n] * acc[n] + consts[129];
}

extern "C" void kernel_launch(void* const* d_in, const int* in_sizes, int n_in,
                              void* d_out, int out_size, void* d_ws, size_t ws_size,
                              hipStream_t stream) {
    const float* x       = (const float*)d_in[0];
    const void*  ei      = d_in[1];
    const float* w1      = (const float*)d_in[2];
    const float* b1      = (const float*)d_in[3];
    const float* bn_g    = (const float*)d_in[4];
    const float* bn_b    = (const float*)d_in[5];
    const float* prelu_a = (const float*)d_in[6];
    const float* w2      = (const float*)d_in[7];
    const float* b2      = (const float*)d_in[8];
    const float* gcn_w   = (const float*)d_in[9];
    const float* gcn_b   = (const float*)d_in[10];
    const float* wb      = (const float*)d_in[11];
    const float* bb      = (const float*)d_in[12];
    float* out = (float*)d_out;

    char* base = (char*)d_ws;
    double*   stats  = (double*)(base + OFF_STATS);
    float*    consts = (float*)(base + OFF_CONST);
    float*    degf   = (float*)(base + OFF_DEG);
    float*    acc    = (float*)(base + OFF_ACC);
    float*    dinv   = (float*)(base + OFF_DINV);
    float*    gs     = (float*)(base + OFF_GS);
    int*      bcnt   = (int*)(base + OFF_BCNT);
    int*      bbase  = (int*)(base + OFF_BBASE);
    int*      pbase  = (int*)(base + OFF_PBASE);
    unsigned* bucket = (unsigned*)(base + OFF_BUCKET);

    // zero stats + consts + degf
    hipMemsetAsync(d_ws, 0, OFF_DEG + PART * P_PARTS * 4, stream);

    count_stats_kernel<<<CBLOCKS, 256, 0, stream>>>(x, ei, stats, bcnt);
    scan_consts_kernel<<<1, 1024, 0, stream>>>(bcnt, bbase, pbase, stats,
        w1, b1, bn_g, bn_b, w2, b2, gcn_w, wb, gcn_b, bb, consts);
    compact_kernel<<<CBLOCKS, 256, 0, stream>>>(ei, bbase, bucket);
    deg_hist_kernel<<<HBLOCKS, T_HIST, 0, stream>>>(bucket, pbase, degf);
    encoder_kernel<<<(N_NODES + 255) / 256, 256, 0, stream>>>(
        x, consts, prelu_a, degf, dinv, gs, acc);
    scatter_hist_kernel<<<HBLOCKS, T_HIST, 0, stream>>>(bucket, pbase, gs, acc);
    finalize_kernel<<<(N_NODES + 255) / 256, 256, 0, stream>>>(dinv, acc, consts, out);
}

// Round 8
// 198.330 us; speedup vs baseline: 1.3640x; 1.3640x over previous
//
#include <hip/hip_runtime.h>
#include <hip/hip_bf16.h>

#define N_NODES 100000
#define N_EDGES 3200000

#define P_PARTS 8
#define PART    12800                    // 8*12800 = 102400 >= N ; 51.2 KB LDS
#define SLICES  64
#define SLICE_E (N_EDGES / SLICES)       // 50000, %4 == 0
#define BLOCKS_H (P_PARTS * SLICES)      // 512
#define T_HIST  1024

#define PACK_BLOCKS 512
#define PACK_T      1024
#define N_QUADS     (N_EDGES / 4)        // 800000

// ---------------- workspace layout (bytes) ----------------
#define OFF_STATS 0        // double[5]     (zeroed)
#define OFF_DEG   1024     // float[102400] (zeroed)
#define OFF_ACC   410624   // float[102400]
#define OFF_DINV  820224   // float[N]
#define OFF_GS    1220224  // float[N]
#define OFF_SRC32 1620224  // int[N_EDGES]  (12.8 MB)
#define OFF_DST32 14420224 // int[N_EDGES]  (12.8 MB)
// total ~27.2 MB

// per-wave int64-vs-int32 detection: high words of first 64 int64 slots
__device__ __forceinline__ bool detect_is64(const void* ei) {
    const int* p = (const int*)ei;
    int lane = threadIdx.x & 63;
    int hi = p[2 * lane + 1];
    unsigned long long m = __ballot(hi != 0);
    return m == 0ull;  // wave-uniform
}

// ---- K1: pack edge index to int32 (coalesced, atomic-free) + BN stats ----
__global__ __launch_bounds__(PACK_T) void pack_stats_kernel(
        const float* __restrict__ x, const void* __restrict__ ei,
        double* __restrict__ stats, int* __restrict__ src32, int* __restrict__ dst32) {
    bool is64 = detect_is64(ei);
    int tid = blockIdx.x * PACK_T + threadIdx.x;

    // ---- pack: grid-stride over edge quads ----
    if (is64) {
        const long long* srcp = (const long long*)ei;
        const long long* dstp = srcp + N_EDGES;
        for (int q = tid; q < N_QUADS; q += PACK_BLOCKS * PACK_T) {
            longlong2 s01 = ((const longlong2*)srcp)[2 * q];
            longlong2 s23 = ((const longlong2*)srcp)[2 * q + 1];
            longlong2 d01 = ((const longlong2*)dstp)[2 * q];
            longlong2 d23 = ((const longlong2*)dstp)[2 * q + 1];
            int4 s4 = make_int4((int)s01.x, (int)s01.y, (int)s23.x, (int)s23.y);
            int4 d4 = make_int4((int)d01.x, (int)d01.y, (int)d23.x, (int)d23.y);
            ((int4*)src32)[q] = s4;
            ((int4*)dst32)[q] = d4;
        }
    } else {
        const int* srcp = (const int*)ei;
        const int* dstp = srcp + N_EDGES;
        for (int q = tid; q < N_QUADS; q += PACK_BLOCKS * PACK_T) {
            ((int4*)src32)[q] = ((const int4*)srcp)[q];
            ((int4*)dst32)[q] = ((const int4*)dstp)[q];
        }
    }

    // ---- stats: one node per thread (only blocks covering nodes participate) ----
    if (blockIdx.x * PACK_T < N_NODES) {
        __shared__ double sh[5][16];
        double a0 = 0, a1 = 0, a2 = 0, a3 = 0, a4 = 0;
        int n = tid;
        if (n < N_NODES) {
            float2 v = ((const float2*)x)[n];
            double x0 = v.x, x1 = v.y;
            a0 = x0; a1 = x1; a2 = x0 * x0; a3 = x1 * x1; a4 = x0 * x1;
        }
        for (int off = 32; off; off >>= 1) {
            a0 += __shfl_down(a0, off);
            a1 += __shfl_down(a1, off);
            a2 += __shfl_down(a2, off);
            a3 += __shfl_down(a3, off);
            a4 += __shfl_down(a4, off);
        }
        int w = threadIdx.x >> 6;
        if ((threadIdx.x & 63) == 0) {
            sh[0][w] = a0; sh[1][w] = a1; sh[2][w] = a2; sh[3][w] = a3; sh[4][w] = a4;
        }
        __syncthreads();
        if (threadIdx.x == 0) {
            double t0 = 0, t1 = 0, t2 = 0, t3 = 0, t4 = 0;
            for (int i = 0; i < 16; i++) {
                t0 += sh[0][i]; t1 += sh[1][i]; t2 += sh[2][i]; t3 += sh[3][i]; t4 += sh[4][i];
            }
            atomicAdd(&stats[0], t0);
            atomicAdd(&stats[1], t1);
            atomicAdd(&stats[2], t2);
            atomicAdd(&stats[3], t3);
            atomicAdd(&stats[4], t4);
        }
    }
}

// ---- K2: LDS-privatized degree histogram over packed dst32 ----
__global__ __launch_bounds__(T_HIST, 8) void deg_hist_kernel(
        const int* __restrict__ dst32, float* __restrict__ degf) {
    __shared__ float hist[PART];
    int p = blockIdx.x & (P_PARTS - 1);
    int slice = blockIdx.x >> 3;
    int base = p * PART;

    for (int i = threadIdx.x; i < PART; i += T_HIST) hist[i] = 0.f;
    __syncthreads();

    int e0 = slice * SLICE_E, e1 = e0 + SLICE_E;
    for (int e = e0 + threadIdx.x * 4; e < e1; e += T_HIST * 4) {
        int4 d4 = *(const int4*)(dst32 + e);
        unsigned l0 = (unsigned)(d4.x - base);
        unsigned l1 = (unsigned)(d4.y - base);
        unsigned l2 = (unsigned)(d4.z - base);
        unsigned l3 = (unsigned)(d4.w - base);
        if (l0 < PART) atomicAdd(&hist[l0], 1.0f);
        if (l1 < PART) atomicAdd(&hist[l1], 1.0f);
        if (l2 < PART) atomicAdd(&hist[l2], 1.0f);
        if (l3 < PART) atomicAdd(&hist[l3], 1.0f);
    }
    __syncthreads();
    for (int i = threadIdx.x; i < PART; i += T_HIST) {
        float v = hist[i];
        if (v != 0.f) unsafeAtomicAdd(&degf[base + i], v);
    }
}

// ---- K3: encoder (scalar): gs[n] = dinv * (GB + sum_c PReLU(Ax0+Bx1+C) U[c]) ----
__global__ void encoder_kernel(const float* __restrict__ x,
                               const double* __restrict__ stats,
                               const float* __restrict__ w1, const float* __restrict__ b1,
                               const float* __restrict__ gamma, const float* __restrict__ beta,
                               const float* __restrict__ prelu_a,
                               const float* __restrict__ w2, const float* __restrict__ b2,
                               const float* __restrict__ gcn_w, const float* __restrict__ wb,
                               const float* __restrict__ degf,
                               float* __restrict__ dinv, float* __restrict__ gs,
                               float* __restrict__ acc) {
    __shared__ float sA[32], sB[32], sC[32], sV[32], sU[32];
    __shared__ float sGB;
    if (threadIdx.x < 32) {
        int c = threadIdx.x;
        double invN = 1.0 / (double)N_NODES;
        double m0 = stats[0] * invN, m1 = stats[1] * invN;
        double e00 = stats[2] * invN, e11 = stats[3] * invN, e01 = stats[4] * invN;
        double a = w1[2 * c], b = w1[2 * c + 1], t = b1[c];
        double meanH = a * m0 + b * m1 + t;
        double eh2 = a * a * e00 + b * b * e11 + 2.0 * a * b * e01 +
                     2.0 * t * (a * m0 + b * m1) + t * t;
        double var = eh2 - meanH * meanH;
        double inv = 1.0 / sqrt(var + 1e-5);
        float sc = (float)((double)gamma[c] * inv);
        float shift = beta[c] - (float)meanH * sc;
        sA[c] = (float)a * sc;
        sB[c] = (float)b * sc;
        sC[c] = (float)t * sc + shift;
        float vc = 0.f;
        for (int j = 0; j < 32; j++) vc += wb[j] * gcn_w[j * 32 + c];
        sV[c] = vc;
        float gb = b2[c] * vc;
        for (int off = 16; off; off >>= 1) gb += __shfl_down(gb, off, 32);
        if (c == 0) sGB = gb;
    }
    __syncthreads();
    if (threadIdx.x < 32) {
        float u = 0.f;
        for (int c = 0; c < 32; c++) u += sV[c] * w2[c * 32 + threadIdx.x];
        sU[threadIdx.x] = u;
    }
    __syncthreads();
    float alpha = prelu_a[0];
    int n = blockIdx.x * blockDim.x + threadIdx.x;
    if (n < N_NODES) {
        float2 xv = ((const float2*)x)[n];
        float g = sGB;
#pragma unroll
        for (int c = 0; c < 32; c++) {
            float hb = sA[c] * xv.x + sB[c] * xv.y + sC[c];
            float pc = hb >= 0.f ? hb : alpha * hb;
            g += pc * sU[c];
        }
        float di = rsqrtf(degf[n] + 1.0f);
        float gg = di * g;
        dinv[n] = di;
        gs[n] = gg;
        acc[n] = gg;  // self-loop term; finalize multiplies by dinv
    }
}

// ---- K4: LDS-privatized scatter over packed src32/dst32 ----
__global__ __launch_bounds__(T_HIST, 8) void scatter_hist_kernel(
        const int* __restrict__ src32, const int* __restrict__ dst32,
        const float* __restrict__ gs, float* __restrict__ acc) {
    __shared__ float hist[PART];
    int p = blockIdx.x & (P_PARTS - 1);
    int slice = blockIdx.x >> 3;
    int base = p * PART;

    for (int i = threadIdx.x; i < PART; i += T_HIST) hist[i] = 0.f;
    __syncthreads();

    int e0 = slice * SLICE_E, e1 = e0 + SLICE_E;
    for (int e = e0 + threadIdx.x * 4; e < e1; e += T_HIST * 4) {
        int4 d4 = *(const int4*)(dst32 + e);
        int4 s4 = *(const int4*)(src32 + e);
        unsigned l0 = (unsigned)(d4.x - base);
        unsigned l1 = (unsigned)(d4.y - base);
        unsigned l2 = (unsigned)(d4.z - base);
        unsigned l3 = (unsigned)(d4.w - base);
        if (l0 < PART) atomicAdd(&hist[l0], gs[s4.x]);
        if (l1 < PART) atomicAdd(&hist[l1], gs[s4.y]);
        if (l2 < PART) atomicAdd(&hist[l2], gs[s4.z]);
        if (l3 < PART) atomicAdd(&hist[l3], gs[s4.w]);
    }
    __syncthreads();
    for (int i = threadIdx.x; i < PART; i += T_HIST) {
        float v = hist[i];
        if (v != 0.f) unsafeAtomicAdd(&acc[base + i], v);
    }
}

// ---- K5: finalize: out = dinv*acc + const ----
__global__ void finalize_kernel(const float* __restrict__ dinv, const float* __restrict__ acc,
                                const float* __restrict__ gcn_b, const float* __restrict__ wb,
                                const float* __restrict__ bb, float* __restrict__ out) {
    __shared__ float scc;
    if (threadIdx.x < 32) {
        float pv = wb[threadIdx.x] * gcn_b[threadIdx.x];
        for (int off = 16; off; off >>= 1) pv += __shfl_down(pv, off, 32);
        if (threadIdx.x == 0) scc = pv + bb[0];
    }
    __syncthreads();
    int n = blockIdx.x * blockDim.x + threadIdx.x;
    if (n < N_NODES) out[n] = dinv[n] * acc[n] + scc;
}

extern "C" void kernel_launch(void* const* d_in, const int* in_sizes, int n_in,
                              void* d_out, int out_size, void* d_ws, size_t ws_size,
                              hipStream_t stream) {
    const float* x       = (const float*)d_in[0];
    const void*  ei      = d_in[1];
    const float* w1      = (const float*)d_in[2];
    const float* b1      = (const float*)d_in[3];
    const float* bn_g    = (const float*)d_in[4];
    const float* bn_b    = (const float*)d_in[5];
    const float* prelu_a = (const float*)d_in[6];
    const float* w2      = (const float*)d_in[7];
    const float* b2      = (const float*)d_in[8];
    const float* gcn_w   = (const float*)d_in[9];
    const float* gcn_b   = (const float*)d_in[10];
    const float* wb      = (const float*)d_in[11];
    const float* bb      = (const float*)d_in[12];
    float* out = (float*)d_out;

    char* base = (char*)d_ws;
    double* stats = (double*)(base + OFF_STATS);
    float*  degf  = (float*)(base + OFF_DEG);
    float*  acc   = (float*)(base + OFF_ACC);
    float*  dinv  = (float*)(base + OFF_DINV);
    float*  gs    = (float*)(base + OFF_GS);
    int*    src32 = (int*)(base + OFF_SRC32);
    int*    dst32 = (int*)(base + OFF_DST32);

    // zero stats + degf (acc fully handled by encoder + skip-zero flush)
    hipMemsetAsync(d_ws, 0, OFF_DEG + PART * P_PARTS * 4, stream);

    pack_stats_kernel<<<PACK_BLOCKS, PACK_T, 0, stream>>>(x, ei, stats, src32, dst32);
    deg_hist_kernel<<<BLOCKS_H, T_HIST, 0, stream>>>(dst32, degf);
    encoder_kernel<<<(N_NODES + 255) / 256, 256, 0, stream>>>(
        x, stats, w1, b1, bn_g, bn_b, prelu_a, w2, b2, gcn_w, wb, degf, dinv, gs, acc);
    scatter_hist_kernel<<<BLOCKS_H, T_HIST, 0, stream>>>(src32, dst32, gs, acc);
    finalize_kernel<<<(N_NODES + 255) / 256, 256, 0, stream>>>(dinv, acc, gcn_b, wb, bb, out);
}